// Round 5
// baseline (651.461 us; speedup 1.0000x reference)
//
#include <hip/hip_runtime.h>
#include <hip/hip_bf16.h>
#include <stdint.h>
#include <stddef.h>

#define Bd  4
#define Sd  1024
#define Hd  1024
#define NHd 16
#define DKd 64
#define SCALEF 0.125f
#define NEGV  -9.0e15f
#define L2E   1.4426950408889634f

typedef __attribute__((ext_vector_type(8))) short bfrag;   // 8 bf16 = 4 VGPRs (MFMA A/B)
typedef __attribute__((ext_vector_type(4))) float facc;    // 4 fp32 (MFMA C/D)
typedef __attribute__((ext_vector_type(4))) float f32x4;   // clang-native float4 (NT-load OK)

typedef __attribute__((address_space(1))) const unsigned int ga_u32;
typedef __attribute__((address_space(3))) unsigned int ls_u32;

__device__ __forceinline__ void gload_lds16(const void* g, void* l) {
  // async global->LDS: global addr per-lane, LDS dest = wave-uniform base + lane*16
  __builtin_amdgcn_global_load_lds((ga_u32*)g, (ls_u32*)l, 16, 0, 0);
}

__device__ __forceinline__ unsigned short f2bf(float f) {
  unsigned int u = __float_as_uint(f);
  u += 0x7fffu + ((u >> 16) & 1u);   // RNE
  return (unsigned short)(u >> 16);
}

// ---------------- fused cast fp32 -> bf16, all 5 arrays, one launch ----------------
__global__ void castk_all(const float* __restrict__ s0, const float* __restrict__ s1,
                          const float* __restrict__ s2, const float* __restrict__ s3,
                          const float* __restrict__ s4,
                          unsigned short* __restrict__ d0, unsigned short* __restrict__ d1,
                          unsigned short* __restrict__ d2, unsigned short* __restrict__ d3,
                          unsigned short* __restrict__ d4) {
  const int id = blockIdx.x;
  const float* s; unsigned short* d; int i;
  if (id < 4096) { s = s0; d = d0; i = id * 256 + threadIdx.x; }
  else {
    const int w = (id - 4096) >> 10;
    s = (w == 0) ? s1 : (w == 1) ? s2 : (w == 2) ? s3 : s4;
    d = (w == 0) ? d1 : (w == 1) ? d2 : (w == 2) ? d3 : d4;
    i = ((id - 4096) & 1023) * 256 + threadIdx.x;
  }
  float4 v = ((const float4*)s)[i];
  ushort4 ov;
  ov.x = f2bf(v.x); ov.y = f2bf(v.y); ov.z = f2bf(v.z); ov.w = f2bf(v.w);
  ((ushort4*)d)[i] = ov;
}

// ---------------- fused QKV projection GEMM ----------------
// z=0 -> q[b,h,s,d], z=1 -> k[b,h,s,d], z=2 -> vt[b,h,d,s] (via LDS transpose)
__global__ __launch_bounds__(256, 3)
void gemm_qkv(const unsigned short* __restrict__ A,
              const unsigned short* __restrict__ W0, const unsigned short* __restrict__ W1,
              const unsigned short* __restrict__ W2,
              const float* __restrict__ b0, const float* __restrict__ b1, const float* __restrict__ b2,
              unsigned short* __restrict__ o0, unsigned short* __restrict__ o1, unsigned short* __restrict__ o2) {
  __shared__ __align__(16) unsigned short smem[128 * 136];
  unsigned short* sA = smem;          // 128*32
  unsigned short* sB = smem + 4096;   // 128*32
  const int z = blockIdx.z;
  const unsigned short* Bm = (z == 0) ? W0 : (z == 1) ? W1 : W2;
  const float* bias = (z == 0) ? b0 : (z == 1) ? b1 : b2;
  unsigned short* out = (z == 0) ? o0 : (z == 1) ? o1 : o2;

  const int m0 = blockIdx.x * 128, n0 = blockIdx.y * 128;
  const int tid = threadIdx.x;
  const int wave = tid >> 6, lane = tid & 63;
  const int quad = lane >> 4, l16 = lane & 15;
  const int wm = wave >> 1, wn = wave & 1;

  facc acc[4][4] = {};

  const int j0 = wave * 128 + lane;
  const int j1 = j0 + 64;
  const int row0 = j0 >> 2, ko0 = (j0 & 3) << 3;
  const int row1 = j1 >> 2, ko1 = (j1 & 3) << 3;
  const size_t aoff0 = (size_t)(m0 + row0) * 1024 + ko0;
  const size_t aoff1 = (size_t)(m0 + row1) * 1024 + ko1;
  const size_t boff0 = (size_t)(n0 + row0) * 1024 + ko0;
  const size_t boff1 = (size_t)(n0 + row1) * 1024 + ko1;
  unsigned short* sA0 = sA + (wave * 2 + 0) * 512;
  unsigned short* sA1 = sA + (wave * 2 + 1) * 512;
  unsigned short* sB0 = sB + (wave * 2 + 0) * 512;
  unsigned short* sB1 = sB + (wave * 2 + 1) * 512;

  for (int k0 = 0; k0 < 1024; k0 += 32) {
    gload_lds16(A + aoff0 + k0, sA0);
    gload_lds16(A + aoff1 + k0, sA1);
    gload_lds16(Bm + boff0 + k0, sB0);
    gload_lds16(Bm + boff1 + k0, sB1);
    __syncthreads();
    bfrag af[4], bf[4];
#pragma unroll
    for (int i = 0; i < 4; ++i) af[i] = *(const bfrag*)(sA + (wm * 64 + i * 16 + l16) * 32 + quad * 8);
#pragma unroll
    for (int j = 0; j < 4; ++j) bf[j] = *(const bfrag*)(sB + (wn * 64 + j * 16 + l16) * 32 + quad * 8);
#pragma unroll
    for (int i = 0; i < 4; ++i)
#pragma unroll
      for (int j = 0; j < 4; ++j)
        acc[i][j] = __builtin_amdgcn_mfma_f32_16x16x32_bf16(af[i], bf[j], acc[i][j], 0, 0, 0);
    __syncthreads();
  }

  if (z < 2) {
#pragma unroll
    for (int i = 0; i < 4; ++i)
#pragma unroll
      for (int j = 0; j < 4; ++j) {
        const int col = n0 + wn * 64 + j * 16 + l16;
        const float bv = bias[col];
        const int h = col >> 6, d = col & 63;
#pragma unroll
        for (int r = 0; r < 4; ++r) {
          const int m = m0 + wm * 64 + i * 16 + quad * 4 + r;
          const int b = m >> 10, s = m & 1023;
          out[(((size_t)(b * NHd + h) * Sd) + s) * DKd + d] = f2bf(acc[i][j][r] + bv);
        }
      }
  } else {
    unsigned short* sT = smem;  // 128 x 136 (padded)
#pragma unroll
    for (int i = 0; i < 4; ++i)
#pragma unroll
      for (int j = 0; j < 4; ++j) {
        const int col = n0 + wn * 64 + j * 16 + l16;
        const float bv = bias[col];
        const int nrow = wn * 64 + j * 16 + l16;
        const int mbase = wm * 64 + i * 16 + quad * 4;
        ushort4 pk;
        pk.x = f2bf(acc[i][j][0] + bv);
        pk.y = f2bf(acc[i][j][1] + bv);
        pk.z = f2bf(acc[i][j][2] + bv);
        pk.w = f2bf(acc[i][j][3] + bv);
        *(ushort4*)(sT + nrow * 136 + mbase) = pk;
      }
    __syncthreads();
    const int bI = m0 >> 10, s0i = m0 & 1023;
#pragma unroll
    for (int it = 0; it < 8; ++it) {
      const int c = tid + it * 256;
      const int row = c >> 4, mc = (c & 15) * 8;
      bfrag vv = *(const bfrag*)(sT + row * 136 + mc);
      const int col = n0 + row, hh = col >> 6, dd = col & 63;
      *(bfrag*)(out + (((size_t)(bI * NHd + hh) * DKd) + dd) * Sd + s0i + mc) = vv;
    }
  }
}

// ---------------- output projection GEMM: 64x128 tile, BK=64, swizzled LDS ----------------
__global__ __launch_bounds__(256, 3)
void gemm_out(const unsigned short* __restrict__ A, const unsigned short* __restrict__ Bm,
              const float* __restrict__ bias, float* __restrict__ out) {
  __shared__ __align__(16) unsigned short sA[64 * 64];    // 8 KB
  __shared__ __align__(16) unsigned short sB[128 * 64];   // 16 KB
  const int m0 = blockIdx.x * 64, n0 = blockIdx.y * 128;
  const int tid = threadIdx.x;
  const int wave = tid >> 6, lane = tid & 63;
  const int quad = lane >> 4, l16 = lane & 15;

  facc acc[8] = {};

  // staging: chunk c holds row=c>>3, logical k-chunk (c&7), stored XOR-swizzled
  const int cA0 = (wave * 2 + 0) * 64 + lane;
  const int cA1 = (wave * 2 + 1) * 64 + lane;
  const int rA0 = cA0 >> 3, kA0 = ((cA0 & 7) ^ (rA0 & 7)) * 8;
  const int rA1 = cA1 >> 3, kA1 = ((cA1 & 7) ^ (rA1 & 7)) * 8;
  const size_t aoff0 = (size_t)(m0 + rA0) * 1024 + kA0;
  const size_t aoff1 = (size_t)(m0 + rA1) * 1024 + kA1;
  size_t boff[4];
#pragma unroll
  for (int i = 0; i < 4; ++i) {
    const int c = (wave * 4 + i) * 64 + lane;
    const int r = c >> 3, kk = ((c & 7) ^ (r & 7)) * 8;
    boff[i] = (size_t)(n0 + r) * 1024 + kk;
  }

  for (int k0 = 0; k0 < 1024; k0 += 64) {
    gload_lds16(A + aoff0 + k0, sA + (wave * 2 + 0) * 512);
    gload_lds16(A + aoff1 + k0, sA + (wave * 2 + 1) * 512);
#pragma unroll
    for (int i = 0; i < 4; ++i)
      gload_lds16(Bm + boff[i] + k0, sB + (wave * 4 + i) * 512);
    __syncthreads();
#pragma unroll
    for (int c2 = 0; c2 < 2; ++c2) {
      const int ko = ((c2 * 4 + quad) ^ (l16 & 7)) * 8;   // unswizzle
      bfrag af = *(const bfrag*)(sA + (wave * 16 + l16) * 64 + ko);
#pragma unroll
      for (int j = 0; j < 8; ++j) {
        bfrag bf = *(const bfrag*)(sB + (j * 16 + l16) * 64 + ko);
        acc[j] = __builtin_amdgcn_mfma_f32_16x16x32_bf16(af, bf, acc[j], 0, 0, 0);
      }
    }
    __syncthreads();
  }

#pragma unroll
  for (int j = 0; j < 8; ++j) {
    const int col = n0 + j * 16 + l16;
    const float bv = bias[col];
#pragma unroll
    for (int r = 0; r < 4; ++r) {
      const int m = m0 + wave * 16 + quad * 4 + r;
      out[(size_t)m * 1024 + col] = acc[j][r] + bv;
    }
  }
}

// ---------------- fused flash attention: swapped-QK^T + split-KV, 8 waves/SIMD ----------------
// grid: 2048 1D blocks x 256 thr. Block = 32 q-rows x full kv. 4 waves:
// wave = (kvhalf<<1)|qhalf; each wave: 16 q-rows (rq = q0+qhalf*16), 8 kv-tiles
// of 64 (kvhalf picks cols 0-511 / 512-1023). Softmax has NO running max
// (logits bounded), so split-KV combine is EXACT and additive: O=O0+O1,
// l=l0+l1 — kvhalf=1 waves dump O-partial+rowsums to LDS, one barrier,
// kvhalf=0 waves add+normalize+store.
// Occupancy: 8 blocks/CU x 256 thr = 2048 thr/CU = 32 waves/CU = 8 waves/SIMD
// (chip max; was 4/SIMD in r0-r4 where 3 different structures all sat at
// ~172us latency-bound with every pipe <15%). 8 waves/SIMD REQUIRES <=64
// VGPR — the allocator already delivers 56 for this body; waves_per_eu(8)
// locks it.  XCD-bijective swizzle keeps each bh's K/V on one XCD's L2.
__global__ __attribute__((amdgpu_flat_work_group_size(256, 256), amdgpu_waves_per_eu(8)))
void attn_kernel(const unsigned short* __restrict__ q,   // [B,NH,S,DK]
                 const unsigned short* __restrict__ k,   // [B,NH,S,DK]
                 const unsigned short* __restrict__ vt,  // [B,NH,DK,S]
                 const float* __restrict__ bias,         // [B,NH,S,S]
                 unsigned short* __restrict__ o)         // [B,S,HID] bf16
{
  __shared__ __align__(16) unsigned int sP[4][16][36];   // 9.2 KB packed-P scratch (per wave)
  __shared__ __align__(16) float sO[2][16][68];          // 8.7 KB kv1 O-partials (per qhalf)
  __shared__ float sL[2][16];                            // kv1 row-sums
  const int p = blockIdx.x;
  const int xcd = p & 7;
  const int g = p >> 3;
  const int bh = ((g >> 5) << 3) | xcd;   // 0..63, bh%8 == xcd
  const int q0 = (g & 31) * 32;
  const int tid = threadIdx.x;
  const int wave = tid >> 6, lane = tid & 63;
  const int qhalf = wave & 1, kvhalf = wave >> 1;
  const int quad = lane >> 4, l16 = lane & 15;
  const int b = bh >> 4, h = bh & 15;

  const unsigned short* qh = q + (size_t)bh * Sd * DKd;
  const unsigned short* kh = k + (size_t)bh * Sd * DKd;
  const unsigned short* vh = vt + (size_t)bh * DKd * Sd;
  const float* bias_h = bias + (size_t)bh * Sd * Sd;
  const int rq = q0 + qhalf * 16;
  const int kvbase = kvhalf * 512;
  unsigned int (*sPw)[36] = sP[wave];

  bfrag qf[2];
#pragma unroll
  for (int c = 0; c < 2; ++c)
    qf[c] = *(const bfrag*)(qh + (size_t)(rq + l16) * DKd + c * 32 + quad * 8);

  facc oacc[4] = {};
  float lsum = 0.f;
  const float SL2 = SCALEF * L2E;

  // bias base: row rq+l16 (this lane's q-row), col kvbase + quad*4 (+ j*16 + koff)
  const float* bpS = bias_h + (size_t)(rq + l16) * Sd + kvbase + quad * 4;
  f32x4 br0 = __builtin_nontemporal_load((const f32x4*)(bpS + 0));
  f32x4 br1 = __builtin_nontemporal_load((const f32x4*)(bpS + 16));
  f32x4 br2 = __builtin_nontemporal_load((const f32x4*)(bpS + 32));
  f32x4 br3 = __builtin_nontemporal_load((const f32x4*)(bpS + 48));

  for (int t = 0; t < 8; ++t) {
    const int koff = t * 64;
    const int k0 = kvbase + koff;
    // ---- S^T = K Q^T : sacc[j][r] = S[k0 + j*16 + quad*4 + r][rq + l16] ----
    facc sacc[4] = {};
#pragma unroll
    for (int c = 0; c < 2; ++c)
#pragma unroll
      for (int j = 0; j < 4; ++j) {
        bfrag kf = *(const bfrag*)(kh + (size_t)(k0 + j * 16 + l16) * DKd + c * 32 + quad * 8);
        sacc[j] = __builtin_amdgcn_mfma_f32_16x16x32_bf16(kf, qf[c], sacc[j], 0, 0, 0);
      }
    // ---- pin bias regs: loads were issued ~1 tile ago, must be resident NOW ----
    asm volatile("" : "+v"(br0), "+v"(br1), "+v"(br2), "+v"(br3));
    // ---- exp/mask on MFMA outputs; pack to bf16 pairs ----
    unsigned int pk[4][2];
#pragma unroll
    for (int j = 0; j < 4; ++j) {
      const f32x4 bb = (j == 0) ? br0 : (j == 1) ? br1 : (j == 2) ? br2 : br3;
      float e0 = __builtin_amdgcn_exp2f(fmaf(sacc[j][0], SL2, bb.x * L2E));
      float e1 = __builtin_amdgcn_exp2f(fmaf(sacc[j][1], SL2, bb.y * L2E));
      float e2 = __builtin_amdgcn_exp2f(fmaf(sacc[j][2], SL2, bb.z * L2E));
      float e3 = __builtin_amdgcn_exp2f(fmaf(sacc[j][3], SL2, bb.w * L2E));
      e0 = (sacc[j][0] == 0.f) ? 0.f : e0;
      e1 = (sacc[j][1] == 0.f) ? 0.f : e1;
      e2 = (sacc[j][2] == 0.f) ? 0.f : e2;
      e3 = (sacc[j][3] == 0.f) ? 0.f : e3;
      lsum += (e0 + e1) + (e2 + e3);
      pk[j][0] = (unsigned int)f2bf(e0) | ((unsigned int)f2bf(e1) << 16);
      pk[j][1] = (unsigned int)f2bf(e2) | ((unsigned int)f2bf(e3) << 16);
    }
    // ---- issue bias prefetch for t+1 (hides under LDS + PV + next QK^T) ----
    if (t < 7) {
      const float* bpn = bpS + koff + 64;
      br0 = __builtin_nontemporal_load((const f32x4*)(bpn + 0));
      br1 = __builtin_nontemporal_load((const f32x4*)(bpn + 16));
      br2 = __builtin_nontemporal_load((const f32x4*)(bpn + 32));
      br3 = __builtin_nontemporal_load((const f32x4*)(bpn + 48));
    }
    // ---- reshape P^T fragments via tiny wave-private LDS ----
#pragma unroll
    for (int j = 0; j < 4; ++j) {
      uint2 w; w.x = pk[j][0]; w.y = pk[j][1];
      *(uint2*)&sPw[l16][j * 8 + quad * 2] = w;
    }
    // ---- O^T += V^T P^T ----
#pragma unroll
    for (int c = 0; c < 2; ++c) {
      bfrag pf = *(const bfrag*)&sPw[l16][c * 16 + quad * 4];
#pragma unroll
      for (int n = 0; n < 4; ++n) {
        bfrag vf = *(const bfrag*)(vh + (size_t)(n * 16 + l16) * Sd + k0 + c * 32 + quad * 8);
        oacc[n] = __builtin_amdgcn_mfma_f32_16x16x32_bf16(vf, pf, oacc[n], 0, 0, 0);
      }
    }
  }

  // ---- per-lane row-sum for this kvhalf: reduce across quads ----
  lsum += __shfl_xor(lsum, 16, 64);
  lsum += __shfl_xor(lsum, 32, 64);

  // ---- split-KV combine (exact: no max-rescaling in this softmax) ----
  if (kvhalf) {
#pragma unroll
    for (int n = 0; n < 4; ++n)
      *(facc*)&sO[qhalf][l16][n * 16 + quad * 4] = oacc[n];
    if (quad == 0) sL[qhalf][l16] = lsum;
  }
  __syncthreads();
  if (!kvhalf) {
    lsum += sL[qhalf][l16];
    const float rinv = 1.0f / lsum;
#pragma unroll
    for (int n = 0; n < 4; ++n) {
      const facc op = *(const facc*)&sO[qhalf][l16][n * 16 + quad * 4];
      oacc[n] += op;
    }
    const size_t rowo = (size_t)(b * Sd + rq + l16) * Hd + h * 64 + quad * 4;
#pragma unroll
    for (int n = 0; n < 4; ++n) {
      ushort4 st;
      st.x = f2bf(oacc[n][0] * rinv);
      st.y = f2bf(oacc[n][1] * rinv);
      st.z = f2bf(oacc[n][2] * rinv);
      st.w = f2bf(oacc[n][3] * rinv);
      *(ushort4*)(o + rowo + n * 16) = st;
    }
  }
}

extern "C" void kernel_launch(void* const* d_in, const int* in_sizes, int n_in,
                              void* d_out, int out_size, void* d_ws, size_t ws_size,
                              hipStream_t stream) {
  const float* batch = (const float*)d_in[0];
  const float* attn_bias = (const float*)d_in[1];
  const float* Wq = (const float*)d_in[2];
  const float* bq = (const float*)d_in[3];
  const float* Wk = (const float*)d_in[4];
  const float* bk = (const float*)d_in[5];
  const float* Wv = (const float*)d_in[6];
  const float* bv = (const float*)d_in[7];
  const float* Wo = (const float*)d_in[8];
  const float* bo = (const float*)d_in[9];
  float* out = (float*)d_out;

  unsigned short* ws = (unsigned short*)d_ws;
  unsigned short* Ab  = ws;                 // 4096x1024
  unsigned short* Wqb = Ab  + 4194304;      // 1024x1024 each
  unsigned short* Wkb = Wqb + 1048576;
  unsigned short* Wvb = Wkb + 1048576;
  unsigned short* Wob = Wvb + 1048576;
  unsigned short* qb  = Wob + 1048576;      // [B,NH,S,DK]
  unsigned short* kb  = qb  + 4194304;
  unsigned short* vtb = kb  + 4194304;      // [B,NH,DK,S]
  unsigned short* ob  = vtb + 4194304;      // [B,S,HID]

  castk_all<<<8192, 256, 0, stream>>>(batch, Wq, Wk, Wv, Wo, Ab, Wqb, Wkb, Wvb, Wob);
  gemm_qkv<<<dim3(32, 8, 3), 256, 0, stream>>>(Ab, Wqb, Wkb, Wvb, bq, bk, bv, qb, kb, vtb);
  attn_kernel<<<dim3(2048), 256, 0, stream>>>(qb, kb, vtb, attn_bias, ob);
  gemm_out<<<dim3(64, 8), 256, 0, stream>>>(ob, Wob, bo, out);
}

// Round 6
// 539.208 us; speedup vs baseline: 1.2082x; 1.2082x over previous
//
#include <hip/hip_runtime.h>
#include <hip/hip_bf16.h>
#include <stdint.h>
#include <stddef.h>

#define Bd  4
#define Sd  1024
#define Hd  1024
#define NHd 16
#define DKd 64
#define SCALEF 0.125f
#define NEGV  -9.0e15f
#define L2E   1.4426950408889634f

typedef __attribute__((ext_vector_type(8))) short bfrag;   // 8 bf16 = 4 VGPRs (MFMA A/B)
typedef __attribute__((ext_vector_type(4))) float facc;    // 4 fp32 (MFMA C/D)
typedef __attribute__((ext_vector_type(4))) float f32x4;   // clang-native float4 (NT-load OK)

typedef __attribute__((address_space(1))) const unsigned int ga_u32;
typedef __attribute__((address_space(3))) unsigned int ls_u32;

__device__ __forceinline__ void gload_lds16(const void* g, void* l) {
  // async global->LDS: global addr per-lane, LDS dest = wave-uniform base + lane*16
  __builtin_amdgcn_global_load_lds((ga_u32*)g, (ls_u32*)l, 16, 0, 0);
}

__device__ __forceinline__ unsigned short f2bf(float f) {
  unsigned int u = __float_as_uint(f);
  u += 0x7fffu + ((u >> 16) & 1u);   // RNE
  return (unsigned short)(u >> 16);
}

// ---------------- fused cast fp32 -> bf16, all 5 arrays, one launch ----------------
__global__ void castk_all(const float* __restrict__ s0, const float* __restrict__ s1,
                          const float* __restrict__ s2, const float* __restrict__ s3,
                          const float* __restrict__ s4,
                          unsigned short* __restrict__ d0, unsigned short* __restrict__ d1,
                          unsigned short* __restrict__ d2, unsigned short* __restrict__ d3,
                          unsigned short* __restrict__ d4) {
  const int id = blockIdx.x;
  const float* s; unsigned short* d; int i;
  if (id < 4096) { s = s0; d = d0; i = id * 256 + threadIdx.x; }
  else {
    const int w = (id - 4096) >> 10;
    s = (w == 0) ? s1 : (w == 1) ? s2 : (w == 2) ? s3 : s4;
    d = (w == 0) ? d1 : (w == 1) ? d2 : (w == 2) ? d3 : d4;
    i = ((id - 4096) & 1023) * 256 + threadIdx.x;
  }
  float4 v = ((const float4*)s)[i];
  ushort4 ov;
  ov.x = f2bf(v.x); ov.y = f2bf(v.y); ov.z = f2bf(v.z); ov.w = f2bf(v.w);
  ((ushort4*)d)[i] = ov;
}

// ---------------- fused QKV projection GEMM ----------------
// z=0 -> q[b,h,s,d], z=1 -> k[b,h,s,d], z=2 -> vt[b,h,d,s] (via LDS transpose)
__global__ __launch_bounds__(256, 3)
void gemm_qkv(const unsigned short* __restrict__ A,
              const unsigned short* __restrict__ W0, const unsigned short* __restrict__ W1,
              const unsigned short* __restrict__ W2,
              const float* __restrict__ b0, const float* __restrict__ b1, const float* __restrict__ b2,
              unsigned short* __restrict__ o0, unsigned short* __restrict__ o1, unsigned short* __restrict__ o2) {
  __shared__ __align__(16) unsigned short smem[128 * 136];
  unsigned short* sA = smem;          // 128*32
  unsigned short* sB = smem + 4096;   // 128*32
  const int z = blockIdx.z;
  const unsigned short* Bm = (z == 0) ? W0 : (z == 1) ? W1 : W2;
  const float* bias = (z == 0) ? b0 : (z == 1) ? b1 : b2;
  unsigned short* out = (z == 0) ? o0 : (z == 1) ? o1 : o2;

  const int m0 = blockIdx.x * 128, n0 = blockIdx.y * 128;
  const int tid = threadIdx.x;
  const int wave = tid >> 6, lane = tid & 63;
  const int quad = lane >> 4, l16 = lane & 15;
  const int wm = wave >> 1, wn = wave & 1;

  facc acc[4][4] = {};

  const int j0 = wave * 128 + lane;
  const int j1 = j0 + 64;
  const int row0 = j0 >> 2, ko0 = (j0 & 3) << 3;
  const int row1 = j1 >> 2, ko1 = (j1 & 3) << 3;
  const size_t aoff0 = (size_t)(m0 + row0) * 1024 + ko0;
  const size_t aoff1 = (size_t)(m0 + row1) * 1024 + ko1;
  const size_t boff0 = (size_t)(n0 + row0) * 1024 + ko0;
  const size_t boff1 = (size_t)(n0 + row1) * 1024 + ko1;
  unsigned short* sA0 = sA + (wave * 2 + 0) * 512;
  unsigned short* sA1 = sA + (wave * 2 + 1) * 512;
  unsigned short* sB0 = sB + (wave * 2 + 0) * 512;
  unsigned short* sB1 = sB + (wave * 2 + 1) * 512;

  for (int k0 = 0; k0 < 1024; k0 += 32) {
    gload_lds16(A + aoff0 + k0, sA0);
    gload_lds16(A + aoff1 + k0, sA1);
    gload_lds16(Bm + boff0 + k0, sB0);
    gload_lds16(Bm + boff1 + k0, sB1);
    __syncthreads();
    bfrag af[4], bf[4];
#pragma unroll
    for (int i = 0; i < 4; ++i) af[i] = *(const bfrag*)(sA + (wm * 64 + i * 16 + l16) * 32 + quad * 8);
#pragma unroll
    for (int j = 0; j < 4; ++j) bf[j] = *(const bfrag*)(sB + (wn * 64 + j * 16 + l16) * 32 + quad * 8);
#pragma unroll
    for (int i = 0; i < 4; ++i)
#pragma unroll
      for (int j = 0; j < 4; ++j)
        acc[i][j] = __builtin_amdgcn_mfma_f32_16x16x32_bf16(af[i], bf[j], acc[i][j], 0, 0, 0);
    __syncthreads();
  }

  if (z < 2) {
#pragma unroll
    for (int i = 0; i < 4; ++i)
#pragma unroll
      for (int j = 0; j < 4; ++j) {
        const int col = n0 + wn * 64 + j * 16 + l16;
        const float bv = bias[col];
        const int h = col >> 6, d = col & 63;
#pragma unroll
        for (int r = 0; r < 4; ++r) {
          const int m = m0 + wm * 64 + i * 16 + quad * 4 + r;
          const int b = m >> 10, s = m & 1023;
          out[(((size_t)(b * NHd + h) * Sd) + s) * DKd + d] = f2bf(acc[i][j][r] + bv);
        }
      }
  } else {
    unsigned short* sT = smem;  // 128 x 136 (padded)
#pragma unroll
    for (int i = 0; i < 4; ++i)
#pragma unroll
      for (int j = 0; j < 4; ++j) {
        const int col = n0 + wn * 64 + j * 16 + l16;
        const float bv = bias[col];
        const int nrow = wn * 64 + j * 16 + l16;
        const int mbase = wm * 64 + i * 16 + quad * 4;
        ushort4 pk;
        pk.x = f2bf(acc[i][j][0] + bv);
        pk.y = f2bf(acc[i][j][1] + bv);
        pk.z = f2bf(acc[i][j][2] + bv);
        pk.w = f2bf(acc[i][j][3] + bv);
        *(ushort4*)(sT + nrow * 136 + mbase) = pk;
      }
    __syncthreads();
    const int bI = m0 >> 10, s0i = m0 & 1023;
#pragma unroll
    for (int it = 0; it < 8; ++it) {
      const int c = tid + it * 256;
      const int row = c >> 4, mc = (c & 15) * 8;
      bfrag vv = *(const bfrag*)(sT + row * 136 + mc);
      const int col = n0 + row, hh = col >> 6, dd = col & 63;
      *(bfrag*)(out + (((size_t)(bI * NHd + hh) * DKd) + dd) * Sd + s0i + mc) = vv;
    }
  }
}

// ---------------- output projection GEMM: 64x128 tile, BK=64, swizzled LDS ----------------
__global__ __launch_bounds__(256, 3)
void gemm_out(const unsigned short* __restrict__ A, const unsigned short* __restrict__ Bm,
              const float* __restrict__ bias, float* __restrict__ out) {
  __shared__ __align__(16) unsigned short sA[64 * 64];    // 8 KB
  __shared__ __align__(16) unsigned short sB[128 * 64];   // 16 KB
  const int m0 = blockIdx.x * 64, n0 = blockIdx.y * 128;
  const int tid = threadIdx.x;
  const int wave = tid >> 6, lane = tid & 63;
  const int quad = lane >> 4, l16 = lane & 15;

  facc acc[8] = {};

  // staging: chunk c holds row=c>>3, logical k-chunk (c&7), stored XOR-swizzled
  const int cA0 = (wave * 2 + 0) * 64 + lane;
  const int cA1 = (wave * 2 + 1) * 64 + lane;
  const int rA0 = cA0 >> 3, kA0 = ((cA0 & 7) ^ (rA0 & 7)) * 8;
  const int rA1 = cA1 >> 3, kA1 = ((cA1 & 7) ^ (rA1 & 7)) * 8;
  const size_t aoff0 = (size_t)(m0 + rA0) * 1024 + kA0;
  const size_t aoff1 = (size_t)(m0 + rA1) * 1024 + kA1;
  size_t boff[4];
#pragma unroll
  for (int i = 0; i < 4; ++i) {
    const int c = (wave * 4 + i) * 64 + lane;
    const int r = c >> 3, kk = ((c & 7) ^ (r & 7)) * 8;
    boff[i] = (size_t)(n0 + r) * 1024 + kk;
  }

  for (int k0 = 0; k0 < 1024; k0 += 64) {
    gload_lds16(A + aoff0 + k0, sA + (wave * 2 + 0) * 512);
    gload_lds16(A + aoff1 + k0, sA + (wave * 2 + 1) * 512);
#pragma unroll
    for (int i = 0; i < 4; ++i)
      gload_lds16(Bm + boff[i] + k0, sB + (wave * 4 + i) * 512);
    __syncthreads();
#pragma unroll
    for (int c2 = 0; c2 < 2; ++c2) {
      const int ko = ((c2 * 4 + quad) ^ (l16 & 7)) * 8;   // unswizzle
      bfrag af = *(const bfrag*)(sA + (wave * 16 + l16) * 64 + ko);
#pragma unroll
      for (int j = 0; j < 8; ++j) {
        bfrag bf = *(const bfrag*)(sB + (j * 16 + l16) * 64 + ko);
        acc[j] = __builtin_amdgcn_mfma_f32_16x16x32_bf16(af, bf, acc[j], 0, 0, 0);
      }
    }
    __syncthreads();
  }

#pragma unroll
  for (int j = 0; j < 8; ++j) {
    const int col = n0 + j * 16 + l16;
    const float bv = bias[col];
#pragma unroll
    for (int r = 0; r < 4; ++r) {
      const int m = m0 + wave * 16 + quad * 4 + r;
      out[(size_t)m * 1024 + col] = acc[j][r] + bv;
    }
  }
}

// ---------------- fused flash attention: swapped-QK^T + split-KV, grid-driven 8 waves/SIMD ----------------
// grid: 4096 1D blocks x 128 thr (2 waves). Block = 16 q-rows; wave = kvhalf
// (cols 0-511 / 512-1023, 8 kv-tiles of 64 each). Softmax has NO running max
// (logits bounded) so the split-KV combine is EXACT: O=O0+O1, l=l0+l1 —
// wave1 dumps O-partial+rowsum to LDS, one barrier, wave0 adds+stores.
// Occupancy comes from the GRID (8192 waves = 32/CU = 8/SIMD), NOT from a
// forced waves_per_eu: r5 proved forcing 8/EU slashes VGPR to 32 and spills
// (WRITE_SIZE 8->388 MB, 289us). This body allocates 56 VGPR naturally (r4),
// <=64, so 8 waves/SIMD are reachable with zero spills; LDS 9 KB/block x 16
// blocks/CU = 144 KB <= 160. r5 also proved the memory system sustains
// 2.6 TB/s at 73% occupancy — the r0-r4 172us plateau was pure latency.
__global__ __attribute__((amdgpu_flat_work_group_size(128, 128)))
void attn_kernel(const unsigned short* __restrict__ q,   // [B,NH,S,DK]
                 const unsigned short* __restrict__ k,   // [B,NH,S,DK]
                 const unsigned short* __restrict__ vt,  // [B,NH,DK,S]
                 const float* __restrict__ bias,         // [B,NH,S,S]
                 unsigned short* __restrict__ o)         // [B,S,HID] bf16
{
  __shared__ __align__(16) unsigned int sP[2][16][36];   // 4.6 KB packed-P scratch (per wave)
  __shared__ __align__(16) float sO[16][68];             // 4.4 KB kv1 O-partials
  __shared__ float sL[16];                               // kv1 row-sums
  const int p = blockIdx.x;
  const int xcd = p & 7;
  const int g = p >> 3;                   // 0..511
  const int bh = ((g >> 6) << 3) | xcd;   // 0..63, bh%8 == xcd (bijective)
  const int q0 = (g & 63) * 16;
  const int tid = threadIdx.x;
  const int wave = tid >> 6, lane = tid & 63;
  const int quad = lane >> 4, l16 = lane & 15;
  const int b = bh >> 4, h = bh & 15;

  const unsigned short* qh = q + (size_t)bh * Sd * DKd;
  const unsigned short* kh = k + (size_t)bh * Sd * DKd;
  const unsigned short* vh = vt + (size_t)bh * DKd * Sd;
  const float* bias_h = bias + (size_t)bh * Sd * Sd;
  const int rq = q0;
  const int kvbase = wave * 512;
  unsigned int (*sPw)[36] = sP[wave];

  bfrag qf[2];
#pragma unroll
  for (int c = 0; c < 2; ++c)
    qf[c] = *(const bfrag*)(qh + (size_t)(rq + l16) * DKd + c * 32 + quad * 8);

  facc oacc[4] = {};
  float lsum = 0.f;
  const float SL2 = SCALEF * L2E;

  // bias base: row rq+l16 (this lane's q-row), col kvbase + quad*4 (+ j*16 + koff)
  const float* bpS = bias_h + (size_t)(rq + l16) * Sd + kvbase + quad * 4;
  f32x4 br0 = __builtin_nontemporal_load((const f32x4*)(bpS + 0));
  f32x4 br1 = __builtin_nontemporal_load((const f32x4*)(bpS + 16));
  f32x4 br2 = __builtin_nontemporal_load((const f32x4*)(bpS + 32));
  f32x4 br3 = __builtin_nontemporal_load((const f32x4*)(bpS + 48));

  for (int t = 0; t < 8; ++t) {
    const int koff = t * 64;
    const int k0 = kvbase + koff;
    // ---- S^T = K Q^T : sacc[j][r] = S[k0 + j*16 + quad*4 + r][rq + l16] ----
    facc sacc[4] = {};
#pragma unroll
    for (int c = 0; c < 2; ++c)
#pragma unroll
      for (int j = 0; j < 4; ++j) {
        bfrag kf = *(const bfrag*)(kh + (size_t)(k0 + j * 16 + l16) * DKd + c * 32 + quad * 8);
        sacc[j] = __builtin_amdgcn_mfma_f32_16x16x32_bf16(kf, qf[c], sacc[j], 0, 0, 0);
      }
    // ---- pin bias regs: loads were issued ~1 tile ago, must be resident NOW ----
    asm volatile("" : "+v"(br0), "+v"(br1), "+v"(br2), "+v"(br3));
    // ---- exp/mask on MFMA outputs; pack to bf16 pairs ----
    unsigned int pk[4][2];
#pragma unroll
    for (int j = 0; j < 4; ++j) {
      const f32x4 bb = (j == 0) ? br0 : (j == 1) ? br1 : (j == 2) ? br2 : br3;
      float e0 = __builtin_amdgcn_exp2f(fmaf(sacc[j][0], SL2, bb.x * L2E));
      float e1 = __builtin_amdgcn_exp2f(fmaf(sacc[j][1], SL2, bb.y * L2E));
      float e2 = __builtin_amdgcn_exp2f(fmaf(sacc[j][2], SL2, bb.z * L2E));
      float e3 = __builtin_amdgcn_exp2f(fmaf(sacc[j][3], SL2, bb.w * L2E));
      e0 = (sacc[j][0] == 0.f) ? 0.f : e0;
      e1 = (sacc[j][1] == 0.f) ? 0.f : e1;
      e2 = (sacc[j][2] == 0.f) ? 0.f : e2;
      e3 = (sacc[j][3] == 0.f) ? 0.f : e3;
      lsum += (e0 + e1) + (e2 + e3);
      pk[j][0] = (unsigned int)f2bf(e0) | ((unsigned int)f2bf(e1) << 16);
      pk[j][1] = (unsigned int)f2bf(e2) | ((unsigned int)f2bf(e3) << 16);
    }
    // ---- issue bias prefetch for t+1 (hides under LDS + PV + next QK^T) ----
    if (t < 7) {
      const float* bpn = bpS + koff + 64;
      br0 = __builtin_nontemporal_load((const f32x4*)(bpn + 0));
      br1 = __builtin_nontemporal_load((const f32x4*)(bpn + 16));
      br2 = __builtin_nontemporal_load((const f32x4*)(bpn + 32));
      br3 = __builtin_nontemporal_load((const f32x4*)(bpn + 48));
    }
    // ---- reshape P^T fragments via tiny wave-private LDS ----
#pragma unroll
    for (int j = 0; j < 4; ++j) {
      uint2 w; w.x = pk[j][0]; w.y = pk[j][1];
      *(uint2*)&sPw[l16][j * 8 + quad * 2] = w;
    }
    // ---- O^T += V^T P^T ----
#pragma unroll
    for (int c = 0; c < 2; ++c) {
      bfrag pf = *(const bfrag*)&sPw[l16][c * 16 + quad * 4];
#pragma unroll
      for (int n = 0; n < 4; ++n) {
        bfrag vf = *(const bfrag*)(vh + (size_t)(n * 16 + l16) * Sd + k0 + c * 32 + quad * 8);
        oacc[n] = __builtin_amdgcn_mfma_f32_16x16x32_bf16(vf, pf, oacc[n], 0, 0, 0);
      }
    }
  }

  // ---- per-lane row-sum for this kvhalf: reduce across quads ----
  lsum += __shfl_xor(lsum, 16, 64);
  lsum += __shfl_xor(lsum, 32, 64);

  // ---- split-KV combine (exact: no max-rescaling in this softmax) ----
  if (wave) {
#pragma unroll
    for (int n = 0; n < 4; ++n)
      *(facc*)&sO[l16][n * 16 + quad * 4] = oacc[n];
    if (quad == 0) sL[l16] = lsum;
  }
  __syncthreads();
  if (!wave) {
    lsum += sL[l16];
    const float rinv = 1.0f / lsum;
#pragma unroll
    for (int n = 0; n < 4; ++n) {
      const facc op = *(const facc*)&sO[l16][n * 16 + quad * 4];
      oacc[n] += op;
    }
    const size_t rowo = (size_t)(b * Sd + rq + l16) * Hd + h * 64 + quad * 4;
#pragma unroll
    for (int n = 0; n < 4; ++n) {
      ushort4 st;
      st.x = f2bf(oacc[n][0] * rinv);
      st.y = f2bf(oacc[n][1] * rinv);
      st.z = f2bf(oacc[n][2] * rinv);
      st.w = f2bf(oacc[n][3] * rinv);
      *(ushort4*)(o + rowo + n * 16) = st;
    }
  }
}

extern "C" void kernel_launch(void* const* d_in, const int* in_sizes, int n_in,
                              void* d_out, int out_size, void* d_ws, size_t ws_size,
                              hipStream_t stream) {
  const float* batch = (const float*)d_in[0];
  const float* attn_bias = (const float*)d_in[1];
  const float* Wq = (const float*)d_in[2];
  const float* bq = (const float*)d_in[3];
  const float* Wk = (const float*)d_in[4];
  const float* bk = (const float*)d_in[5];
  const float* Wv = (const float*)d_in[6];
  const float* bv = (const float*)d_in[7];
  const float* Wo = (const float*)d_in[8];
  const float* bo = (const float*)d_in[9];
  float* out = (float*)d_out;

  unsigned short* ws = (unsigned short*)d_ws;
  unsigned short* Ab  = ws;                 // 4096x1024
  unsigned short* Wqb = Ab  + 4194304;      // 1024x1024 each
  unsigned short* Wkb = Wqb + 1048576;
  unsigned short* Wvb = Wkb + 1048576;
  unsigned short* Wob = Wvb + 1048576;
  unsigned short* qb  = Wob + 1048576;      // [B,NH,S,DK]
  unsigned short* kb  = qb  + 4194304;
  unsigned short* vtb = kb  + 4194304;      // [B,NH,DK,S]
  unsigned short* ob  = vtb + 4194304;      // [B,S,HID]

  castk_all<<<8192, 256, 0, stream>>>(batch, Wq, Wk, Wv, Wo, Ab, Wqb, Wkb, Wvb, Wob);
  gemm_qkv<<<dim3(32, 8, 3), 256, 0, stream>>>(Ab, Wqb, Wkb, Wvb, bq, bk, bv, qb, kb, vtb);
  attn_kernel<<<dim3(4096), 128, 0, stream>>>(qb, kb, vtb, attn_bias, ob);
  gemm_out<<<dim3(64, 8), 256, 0, stream>>>(ob, Wob, bo, out);
}

// Round 7
// 452.231 us; speedup vs baseline: 1.4405x; 1.1923x over previous
//
#include <hip/hip_runtime.h>
#include <hip/hip_bf16.h>
#include <stdint.h>
#include <stddef.h>

#define Bd  4
#define Sd  1024
#define Hd  1024
#define NHd 16
#define DKd 64
#define SCALEF 0.125f
#define NEGV  -9.0e15f
#define L2E   1.4426950408889634f

typedef __attribute__((ext_vector_type(8))) short bfrag;   // 8 bf16 = 4 VGPRs (MFMA A/B)
typedef __attribute__((ext_vector_type(4))) float facc;    // 4 fp32 (MFMA C/D)
typedef __attribute__((ext_vector_type(4))) float f32x4;   // clang-native float4 (NT-load OK)

typedef __attribute__((address_space(1))) const unsigned int ga_u32;
typedef __attribute__((address_space(3))) unsigned int ls_u32;

__device__ __forceinline__ void gload_lds16(const void* g, void* l) {
  // async global->LDS: global addr per-lane, LDS dest = wave-uniform base + lane*16
  __builtin_amdgcn_global_load_lds((ga_u32*)g, (ls_u32*)l, 16, 0, 0);
}

__device__ __forceinline__ unsigned short f2bf(float f) {
  unsigned int u = __float_as_uint(f);
  u += 0x7fffu + ((u >> 16) & 1u);   // RNE
  return (unsigned short)(u >> 16);
}

// ---------------- fused cast fp32 -> bf16, all 5 arrays, one launch ----------------
__global__ void castk_all(const float* __restrict__ s0, const float* __restrict__ s1,
                          const float* __restrict__ s2, const float* __restrict__ s3,
                          const float* __restrict__ s4,
                          unsigned short* __restrict__ d0, unsigned short* __restrict__ d1,
                          unsigned short* __restrict__ d2, unsigned short* __restrict__ d3,
                          unsigned short* __restrict__ d4) {
  const int id = blockIdx.x;
  const float* s; unsigned short* d; int i;
  if (id < 4096) { s = s0; d = d0; i = id * 256 + threadIdx.x; }
  else {
    const int w = (id - 4096) >> 10;
    s = (w == 0) ? s1 : (w == 1) ? s2 : (w == 2) ? s3 : s4;
    d = (w == 0) ? d1 : (w == 1) ? d2 : (w == 2) ? d3 : d4;
    i = ((id - 4096) & 1023) * 256 + threadIdx.x;
  }
  float4 v = ((const float4*)s)[i];
  ushort4 ov;
  ov.x = f2bf(v.x); ov.y = f2bf(v.y); ov.z = f2bf(v.z); ov.w = f2bf(v.w);
  ((ushort4*)d)[i] = ov;
}

// ---------------- fused QKV projection GEMM ----------------
// z=0 -> q[b,h,s,d], z=1 -> k[b,h,s,d], z=2 -> vt[b,h,d,s] (via LDS transpose)
__global__ __launch_bounds__(256, 3)
void gemm_qkv(const unsigned short* __restrict__ A,
              const unsigned short* __restrict__ W0, const unsigned short* __restrict__ W1,
              const unsigned short* __restrict__ W2,
              const float* __restrict__ b0, const float* __restrict__ b1, const float* __restrict__ b2,
              unsigned short* __restrict__ o0, unsigned short* __restrict__ o1, unsigned short* __restrict__ o2) {
  __shared__ __align__(16) unsigned short smem[128 * 136];
  unsigned short* sA = smem;          // 128*32
  unsigned short* sB = smem + 4096;   // 128*32
  const int z = blockIdx.z;
  const unsigned short* Bm = (z == 0) ? W0 : (z == 1) ? W1 : W2;
  const float* bias = (z == 0) ? b0 : (z == 1) ? b1 : b2;
  unsigned short* out = (z == 0) ? o0 : (z == 1) ? o1 : o2;

  const int m0 = blockIdx.x * 128, n0 = blockIdx.y * 128;
  const int tid = threadIdx.x;
  const int wave = tid >> 6, lane = tid & 63;
  const int quad = lane >> 4, l16 = lane & 15;
  const int wm = wave >> 1, wn = wave & 1;

  facc acc[4][4] = {};

  const int j0 = wave * 128 + lane;
  const int j1 = j0 + 64;
  const int row0 = j0 >> 2, ko0 = (j0 & 3) << 3;
  const int row1 = j1 >> 2, ko1 = (j1 & 3) << 3;
  const size_t aoff0 = (size_t)(m0 + row0) * 1024 + ko0;
  const size_t aoff1 = (size_t)(m0 + row1) * 1024 + ko1;
  const size_t boff0 = (size_t)(n0 + row0) * 1024 + ko0;
  const size_t boff1 = (size_t)(n0 + row1) * 1024 + ko1;
  unsigned short* sA0 = sA + (wave * 2 + 0) * 512;
  unsigned short* sA1 = sA + (wave * 2 + 1) * 512;
  unsigned short* sB0 = sB + (wave * 2 + 0) * 512;
  unsigned short* sB1 = sB + (wave * 2 + 1) * 512;

  for (int k0 = 0; k0 < 1024; k0 += 32) {
    gload_lds16(A + aoff0 + k0, sA0);
    gload_lds16(A + aoff1 + k0, sA1);
    gload_lds16(Bm + boff0 + k0, sB0);
    gload_lds16(Bm + boff1 + k0, sB1);
    __syncthreads();
    bfrag af[4], bf[4];
#pragma unroll
    for (int i = 0; i < 4; ++i) af[i] = *(const bfrag*)(sA + (wm * 64 + i * 16 + l16) * 32 + quad * 8);
#pragma unroll
    for (int j = 0; j < 4; ++j) bf[j] = *(const bfrag*)(sB + (wn * 64 + j * 16 + l16) * 32 + quad * 8);
#pragma unroll
    for (int i = 0; i < 4; ++i)
#pragma unroll
      for (int j = 0; j < 4; ++j)
        acc[i][j] = __builtin_amdgcn_mfma_f32_16x16x32_bf16(af[i], bf[j], acc[i][j], 0, 0, 0);
    __syncthreads();
  }

  if (z < 2) {
#pragma unroll
    for (int i = 0; i < 4; ++i)
#pragma unroll
      for (int j = 0; j < 4; ++j) {
        const int col = n0 + wn * 64 + j * 16 + l16;
        const float bv = bias[col];
        const int h = col >> 6, d = col & 63;
#pragma unroll
        for (int r = 0; r < 4; ++r) {
          const int m = m0 + wm * 64 + i * 16 + quad * 4 + r;
          const int b = m >> 10, s = m & 1023;
          out[(((size_t)(b * NHd + h) * Sd) + s) * DKd + d] = f2bf(acc[i][j][r] + bv);
        }
      }
  } else {
    unsigned short* sT = smem;  // 128 x 136 (padded)
#pragma unroll
    for (int i = 0; i < 4; ++i)
#pragma unroll
      for (int j = 0; j < 4; ++j) {
        const int col = n0 + wn * 64 + j * 16 + l16;
        const float bv = bias[col];
        const int nrow = wn * 64 + j * 16 + l16;
        const int mbase = wm * 64 + i * 16 + quad * 4;
        ushort4 pk;
        pk.x = f2bf(acc[i][j][0] + bv);
        pk.y = f2bf(acc[i][j][1] + bv);
        pk.z = f2bf(acc[i][j][2] + bv);
        pk.w = f2bf(acc[i][j][3] + bv);
        *(ushort4*)(sT + nrow * 136 + mbase) = pk;
      }
    __syncthreads();
    const int bI = m0 >> 10, s0i = m0 & 1023;
#pragma unroll
    for (int it = 0; it < 8; ++it) {
      const int c = tid + it * 256;
      const int row = c >> 4, mc = (c & 15) * 8;
      bfrag vv = *(const bfrag*)(sT + row * 136 + mc);
      const int col = n0 + row, hh = col >> 6, dd = col & 63;
      *(bfrag*)(out + (((size_t)(bI * NHd + hh) * DKd) + dd) * Sd + s0i + mc) = vv;
    }
  }
}

// ---------------- output projection GEMM: 64x128 tile, BK=64, swizzled LDS ----------------
__global__ __launch_bounds__(256, 3)
void gemm_out(const unsigned short* __restrict__ A, const unsigned short* __restrict__ Bm,
              const float* __restrict__ bias, float* __restrict__ out) {
  __shared__ __align__(16) unsigned short sA[64 * 64];    // 8 KB
  __shared__ __align__(16) unsigned short sB[128 * 64];   // 16 KB
  const int m0 = blockIdx.x * 64, n0 = blockIdx.y * 128;
  const int tid = threadIdx.x;
  const int wave = tid >> 6, lane = tid & 63;
  const int quad = lane >> 4, l16 = lane & 15;

  facc acc[8] = {};

  // staging: chunk c holds row=c>>3, logical k-chunk (c&7), stored XOR-swizzled
  const int cA0 = (wave * 2 + 0) * 64 + lane;
  const int cA1 = (wave * 2 + 1) * 64 + lane;
  const int rA0 = cA0 >> 3, kA0 = ((cA0 & 7) ^ (rA0 & 7)) * 8;
  const int rA1 = cA1 >> 3, kA1 = ((cA1 & 7) ^ (rA1 & 7)) * 8;
  const size_t aoff0 = (size_t)(m0 + rA0) * 1024 + kA0;
  const size_t aoff1 = (size_t)(m0 + rA1) * 1024 + kA1;
  size_t boff[4];
#pragma unroll
  for (int i = 0; i < 4; ++i) {
    const int c = (wave * 4 + i) * 64 + lane;
    const int r = c >> 3, kk = ((c & 7) ^ (r & 7)) * 8;
    boff[i] = (size_t)(n0 + r) * 1024 + kk;
  }

  for (int k0 = 0; k0 < 1024; k0 += 64) {
    gload_lds16(A + aoff0 + k0, sA + (wave * 2 + 0) * 512);
    gload_lds16(A + aoff1 + k0, sA + (wave * 2 + 1) * 512);
#pragma unroll
    for (int i = 0; i < 4; ++i)
      gload_lds16(Bm + boff[i] + k0, sB + (wave * 4 + i) * 512);
    __syncthreads();
#pragma unroll
    for (int c2 = 0; c2 < 2; ++c2) {
      const int ko = ((c2 * 4 + quad) ^ (l16 & 7)) * 8;   // unswizzle
      bfrag af = *(const bfrag*)(sA + (wave * 16 + l16) * 64 + ko);
#pragma unroll
      for (int j = 0; j < 8; ++j) {
        bfrag bf = *(const bfrag*)(sB + (j * 16 + l16) * 64 + ko);
        acc[j] = __builtin_amdgcn_mfma_f32_16x16x32_bf16(af, bf, acc[j], 0, 0, 0);
      }
    }
    __syncthreads();
  }

#pragma unroll
  for (int j = 0; j < 8; ++j) {
    const int col = n0 + j * 16 + l16;
    const float bv = bias[col];
#pragma unroll
    for (int r = 0; r < 4; ++r) {
      const int m = m0 + wave * 16 + quad * 4 + r;
      out[(size_t)m * 1024 + col] = acc[j][r] + bv;
    }
  }
}

// ---------------- fused flash attention: LDS-staged K/V shared by 8 waves ----------------
// grid: 512 blocks x 512 thr (8 waves) = exactly 2 blocks/CU, no tail.
// Block = 128 q-rows (16/wave) x full KV; per kv-tile (64 rows) K and V are
// DMA'd ONCE into XOR-swizzled LDS (global_load_lds, pre-swizzled global src
// per G21) and read by all 8 waves -> per-wave VMEM drops 20->6 instrs/tile
// and K/V L2 traffic drops 8x. r6 evidence: time identical with bias in L3
// (48 GB/s HBM) => not BW-bound; occupancy pinned at ~3 waves/SIMD by the
// unified VGPR+AGPR file (arch 72 + acc 64) in ALL rounds => the 174us was
// VMEM-queueing latency on 20 loads/tile at 3 waves/SIMD. This cuts the
// loads instead of chasing waves. Swizzle: slot ^= row&7 within each 128B
// row (m214's +89% fix); compute body is byte-identical to the verified r4
// wave body (swapped QK^T, register softmax, sP reshape, PV).
__global__ __attribute__((amdgpu_flat_work_group_size(512, 512), amdgpu_waves_per_eu(4, 4)))
void attn_kernel(const unsigned short* __restrict__ q,   // [B,NH,S,DK]
                 const unsigned short* __restrict__ k,   // [B,NH,S,DK]
                 const unsigned short* __restrict__ vt,  // [B,NH,DK,S]
                 const float* __restrict__ bias,         // [B,NH,S,S]
                 unsigned short* __restrict__ o)         // [B,S,HID] bf16
{
  __shared__ __align__(16) unsigned short sK[2][64 * 64];  // 2 x 8 KB, swizzled
  __shared__ __align__(16) unsigned short sV[2][64 * 64];  // 2 x 8 KB, swizzled
  __shared__ __align__(16) unsigned int sP[8][16][36];     // 18 KB packed-P (per wave)

  const int p = blockIdx.x;
  const int xcd = p & 7;
  const int g = p >> 3;                   // 0..63
  const int bh = ((g >> 3) << 3) | xcd;   // 8 bh per XCD (bijective)
  const int qblk = g & 7;
  const int tid = threadIdx.x;
  const int wave = tid >> 6, lane = tid & 63;
  const int quad = lane >> 4, l16 = lane & 15;
  const int b = bh >> 4, h = bh & 15;

  const unsigned short* qh = q + (size_t)bh * Sd * DKd;
  const unsigned short* kh = k + (size_t)bh * Sd * DKd;
  const unsigned short* vh = vt + (size_t)bh * DKd * Sd;
  const float* bias_h = bias + (size_t)bh * Sd * Sd;
  const int rq = qblk * 128 + wave * 16;
  unsigned int (*sPw)[36] = sP[wave];

  // ---- staging geometry: wave stages rows [wave*8, wave*8+8) of each tile ----
  // lane covers tile-row srow = wave*8 + lane/8, phys 16B-slot lane&7;
  // source slot pre-swizzled so LDS[row][p] = G[row][p ^ (row&7)]
  const int srow = wave * 8 + (lane >> 3);
  const int sslot = (lane & 7) ^ (srow & 7);
  const unsigned short* srcK = kh + (size_t)srow * DKd + sslot * 8;
  const unsigned short* srcV = vh + (size_t)srow * Sd + sslot * 8;
  unsigned short* dK0 = sK[0] + wave * 512;
  unsigned short* dK1 = sK[1] + wave * 512;
  unsigned short* dV0 = sV[0] + wave * 512;
  unsigned short* dV1 = sV[1] + wave * 512;

  // swizzled fragment slot offsets (elements): logical slot c*4+quad, row&7 = l16&7
  const int xs0 = ((0 + quad) ^ (l16 & 7)) * 8;
  const int xs1 = ((4 + quad) ^ (l16 & 7)) * 8;

  bfrag qf[2];
#pragma unroll
  for (int c = 0; c < 2; ++c)
    qf[c] = *(const bfrag*)(qh + (size_t)(rq + l16) * DKd + c * 32 + quad * 8);

  facc oacc[4] = {};
  float lsum = 0.f;
  const float SL2 = SCALEF * L2E;

  // bias: row rq+l16 (this lane's q-row), col quad*4 (+ j*16 + t*64)
  const float* bpS = bias_h + (size_t)(rq + l16) * Sd + quad * 4;
  f32x4 br0 = __builtin_nontemporal_load((const f32x4*)(bpS + 0));
  f32x4 br1 = __builtin_nontemporal_load((const f32x4*)(bpS + 16));
  f32x4 br2 = __builtin_nontemporal_load((const f32x4*)(bpS + 32));
  f32x4 br3 = __builtin_nontemporal_load((const f32x4*)(bpS + 48));

  // ---- prologue: stage tile 0 into buffer 0 ----
  gload_lds16(srcK, dK0);
  gload_lds16(srcV, dV0);
  __syncthreads();   // drains vmcnt before barrier -> tile 0 resident

  for (int t = 0; t < 16; ++t) {
    const int bb = t & 1;
    // ---- issue DMA for tile t+1 into the other buffer (no wait) ----
    if (t < 15) {
      const int kn = (t + 1) * 64;
      gload_lds16(srcK + (size_t)kn * DKd, bb ? dK0 : dK1);
      gload_lds16(srcV + kn, bb ? dV0 : dV1);
    }
    const unsigned short* sKb = sK[bb];
    const unsigned short* sVb = sV[bb];
    // ---- S^T = K Q^T from LDS: sacc[j][r] = S[t*64 + j*16+quad*4+r][rq+l16] ----
    facc sacc[4] = {};
#pragma unroll
    for (int j = 0; j < 4; ++j) {
      bfrag kf = *(const bfrag*)(sKb + (j * 16 + l16) * 64 + xs0);
      sacc[j] = __builtin_amdgcn_mfma_f32_16x16x32_bf16(kf, qf[0], sacc[j], 0, 0, 0);
    }
#pragma unroll
    for (int j = 0; j < 4; ++j) {
      bfrag kf = *(const bfrag*)(sKb + (j * 16 + l16) * 64 + xs1);
      sacc[j] = __builtin_amdgcn_mfma_f32_16x16x32_bf16(kf, qf[1], sacc[j], 0, 0, 0);
    }
    // ---- pin bias regs (loads issued one tile ago) ----
    asm volatile("" : "+v"(br0), "+v"(br1), "+v"(br2), "+v"(br3));
    // ---- exp/mask on MFMA outputs; pack to bf16 pairs ----
    unsigned int pk[4][2];
#pragma unroll
    for (int j = 0; j < 4; ++j) {
      const f32x4 bv = (j == 0) ? br0 : (j == 1) ? br1 : (j == 2) ? br2 : br3;
      float e0 = __builtin_amdgcn_exp2f(fmaf(sacc[j][0], SL2, bv.x * L2E));
      float e1 = __builtin_amdgcn_exp2f(fmaf(sacc[j][1], SL2, bv.y * L2E));
      float e2 = __builtin_amdgcn_exp2f(fmaf(sacc[j][2], SL2, bv.z * L2E));
      float e3 = __builtin_amdgcn_exp2f(fmaf(sacc[j][3], SL2, bv.w * L2E));
      e0 = (sacc[j][0] == 0.f) ? 0.f : e0;
      e1 = (sacc[j][1] == 0.f) ? 0.f : e1;
      e2 = (sacc[j][2] == 0.f) ? 0.f : e2;
      e3 = (sacc[j][3] == 0.f) ? 0.f : e3;
      lsum += (e0 + e1) + (e2 + e3);
      pk[j][0] = (unsigned int)f2bf(e0) | ((unsigned int)f2bf(e1) << 16);
      pk[j][1] = (unsigned int)f2bf(e2) | ((unsigned int)f2bf(e3) << 16);
    }
    // ---- bias prefetch for t+1 (hides under sP + PV + barrier + next QK^T) ----
    if (t < 15) {
      const float* bpn = bpS + (t + 1) * 64;
      br0 = __builtin_nontemporal_load((const f32x4*)(bpn + 0));
      br1 = __builtin_nontemporal_load((const f32x4*)(bpn + 16));
      br2 = __builtin_nontemporal_load((const f32x4*)(bpn + 32));
      br3 = __builtin_nontemporal_load((const f32x4*)(bpn + 48));
    }
    // ---- reshape P^T fragments via wave-private LDS ----
#pragma unroll
    for (int j = 0; j < 4; ++j) {
      uint2 w; w.x = pk[j][0]; w.y = pk[j][1];
      *(uint2*)&sPw[l16][j * 8 + quad * 2] = w;
    }
    // ---- O^T += V^T P^T from LDS ----
#pragma unroll
    for (int c = 0; c < 2; ++c) {
      bfrag pf = *(const bfrag*)&sPw[l16][c * 16 + quad * 4];
      const int xsc = c ? xs1 : xs0;
#pragma unroll
      for (int n = 0; n < 4; ++n) {
        bfrag vf = *(const bfrag*)(sVb + (n * 16 + l16) * 64 + xsc);
        oacc[n] = __builtin_amdgcn_mfma_f32_16x16x32_bf16(vf, pf, oacc[n], 0, 0, 0);
      }
    }
    // ---- barrier: all waves done reading buf bb; DMA into buf bb^1 drained ----
    __syncthreads();
  }

  // ---- row-sum: lane owns q-row l16; partials across quads ----
  lsum += __shfl_xor(lsum, 16, 64);
  lsum += __shfl_xor(lsum, 32, 64);
  const float rinv = 1.0f / lsum;

  const size_t rowo = (size_t)(b * Sd + rq + l16) * Hd + h * 64 + quad * 4;
#pragma unroll
  for (int n = 0; n < 4; ++n) {
    ushort4 st;
    st.x = f2bf(oacc[n][0] * rinv);
    st.y = f2bf(oacc[n][1] * rinv);
    st.z = f2bf(oacc[n][2] * rinv);
    st.w = f2bf(oacc[n][3] * rinv);
    *(ushort4*)(o + rowo + n * 16) = st;
  }
}

extern "C" void kernel_launch(void* const* d_in, const int* in_sizes, int n_in,
                              void* d_out, int out_size, void* d_ws, size_t ws_size,
                              hipStream_t stream) {
  const float* batch = (const float*)d_in[0];
  const float* attn_bias = (const float*)d_in[1];
  const float* Wq = (const float*)d_in[2];
  const float* bq = (const float*)d_in[3];
  const float* Wk = (const float*)d_in[4];
  const float* bk = (const float*)d_in[5];
  const float* Wv = (const float*)d_in[6];
  const float* bv = (const float*)d_in[7];
  const float* Wo = (const float*)d_in[8];
  const float* bo = (const float*)d_in[9];
  float* out = (float*)d_out;

  unsigned short* ws = (unsigned short*)d_ws;
  unsigned short* Ab  = ws;                 // 4096x1024
  unsigned short* Wqb = Ab  + 4194304;      // 1024x1024 each
  unsigned short* Wkb = Wqb + 1048576;
  unsigned short* Wvb = Wkb + 1048576;
  unsigned short* Wob = Wvb + 1048576;
  unsigned short* qb  = Wob + 1048576;      // [B,NH,S,DK]
  unsigned short* kb  = qb  + 4194304;
  unsigned short* vtb = kb  + 4194304;      // [B,NH,DK,S]
  unsigned short* ob  = vtb + 4194304;      // [B,S,HID]

  castk_all<<<8192, 256, 0, stream>>>(batch, Wq, Wk, Wv, Wo, Ab, Wqb, Wkb, Wvb, Wob);
  gemm_qkv<<<dim3(32, 8, 3), 256, 0, stream>>>(Ab, Wqb, Wkb, Wvb, bq, bk, bv, qb, kb, vtb);
  attn_kernel<<<dim3(512), 512, 0, stream>>>(qb, kb, vtb, attn_bias, ob);
  gemm_out<<<dim3(64, 8), 256, 0, stream>>>(ob, Wob, bo, out);
}

// Round 9
// 450.250 us; speedup vs baseline: 1.4469x; 1.0044x over previous
//
#include <hip/hip_runtime.h>
#include <hip/hip_bf16.h>
#include <stdint.h>
#include <stddef.h>

#define Bd  4
#define Sd  1024
#define Hd  1024
#define NHd 16
#define DKd 64
#define SCALEF 0.125f
#define NEGV  -9.0e15f
#define L2E   1.4426950408889634f

typedef __attribute__((ext_vector_type(8))) short bfrag;   // 8 bf16 = 4 VGPRs (MFMA A/B)
typedef __attribute__((ext_vector_type(4))) float facc;    // 4 fp32 (MFMA C/D)
typedef __attribute__((ext_vector_type(4))) float f32x4;   // clang-native float4 (NT-load OK)

typedef __attribute__((address_space(1))) const unsigned int ga_u32;
typedef __attribute__((address_space(3))) unsigned int ls_u32;

__device__ __forceinline__ void gload_lds16(const void* g, void* l) {
  // async global->LDS: global addr per-lane, LDS dest = wave-uniform base + lane*16
  __builtin_amdgcn_global_load_lds((ga_u32*)g, (ls_u32*)l, 16, 0, 0);
}

__device__ __forceinline__ unsigned short f2bf(float f) {
  unsigned int u = __float_as_uint(f);
  u += 0x7fffu + ((u >> 16) & 1u);   // RNE
  return (unsigned short)(u >> 16);
}

// ---------------- fused cast fp32 -> bf16, all 5 arrays, one launch ----------------
__global__ void castk_all(const float* __restrict__ s0, const float* __restrict__ s1,
                          const float* __restrict__ s2, const float* __restrict__ s3,
                          const float* __restrict__ s4,
                          unsigned short* __restrict__ d0, unsigned short* __restrict__ d1,
                          unsigned short* __restrict__ d2, unsigned short* __restrict__ d3,
                          unsigned short* __restrict__ d4) {
  const int id = blockIdx.x;
  const float* s; unsigned short* d; int i;
  if (id < 4096) { s = s0; d = d0; i = id * 256 + threadIdx.x; }
  else {
    const int w = (id - 4096) >> 10;
    s = (w == 0) ? s1 : (w == 1) ? s2 : (w == 2) ? s3 : s4;
    d = (w == 0) ? d1 : (w == 1) ? d2 : (w == 2) ? d3 : d4;
    i = ((id - 4096) & 1023) * 256 + threadIdx.x;
  }
  float4 v = ((const float4*)s)[i];
  ushort4 ov;
  ov.x = f2bf(v.x); ov.y = f2bf(v.y); ov.z = f2bf(v.z); ov.w = f2bf(v.w);
  ((ushort4*)d)[i] = ov;
}

// ---------------- fused QKV projection GEMM (2-phase double-buffered staging) ----------------
// z=0 -> q[b,h,s,d], z=1 -> k[b,h,s,d], z=2 -> vt[b,h,d,s] (via LDS transpose)
// T3-minimal pipeline: issue global_load_lds for K-step t+1 BEFORE computing
// step t; ONE barrier per step (implicit vmcnt(0) drain covers the DMA).
// NOTE: no local arrays of LDS pointers (addrspacecast static-init fails on
// gfx950) — buffer bases computed by offset arithmetic each iteration.
__global__ __launch_bounds__(256, 3)
void gemm_qkv(const unsigned short* __restrict__ A,
              const unsigned short* __restrict__ W0, const unsigned short* __restrict__ W1,
              const unsigned short* __restrict__ W2,
              const float* __restrict__ b0, const float* __restrict__ b1, const float* __restrict__ b2,
              unsigned short* __restrict__ o0, unsigned short* __restrict__ o1, unsigned short* __restrict__ o2) {
  __shared__ __align__(16) unsigned short smem[128 * 136];  // 34.8 KB; dbuf uses 32 KB, sT reuses
  const int z = blockIdx.z;
  const unsigned short* Bm = (z == 0) ? W0 : (z == 1) ? W1 : W2;
  const float* bias = (z == 0) ? b0 : (z == 1) ? b1 : b2;
  unsigned short* out = (z == 0) ? o0 : (z == 1) ? o1 : o2;

  const int m0 = blockIdx.x * 128, n0 = blockIdx.y * 128;
  const int tid = threadIdx.x;
  const int wave = tid >> 6, lane = tid & 63;
  const int quad = lane >> 4, l16 = lane & 15;
  const int wm = wave >> 1, wn = wave & 1;

  facc acc[4][4] = {};

  const int j0 = wave * 128 + lane;
  const int j1 = j0 + 64;
  const int row0 = j0 >> 2, ko0 = (j0 & 3) << 3;
  const int row1 = j1 >> 2, ko1 = (j1 & 3) << 3;
  const size_t aoff0 = (size_t)(m0 + row0) * 1024 + ko0;
  const size_t aoff1 = (size_t)(m0 + row1) * 1024 + ko1;
  const size_t boff0 = (size_t)(n0 + row0) * 1024 + ko0;
  const size_t boff1 = (size_t)(n0 + row1) * 1024 + ko1;

  // layout: [A0 | A1 | B0 | B1], each 4096 ushorts (128x32)
  const int stA = (wave * 2 + 0) * 512;
  const int stA1i = (wave * 2 + 1) * 512;

  // prologue: stage K-step 0 into buffer 0
  gload_lds16(A + aoff0, smem + stA);
  gload_lds16(A + aoff1, smem + stA1i);
  gload_lds16(Bm + boff0, smem + 8192 + stA);
  gload_lds16(Bm + boff1, smem + 8192 + stA1i);
  __syncthreads();

  for (int k0 = 0; k0 < 1024; k0 += 32) {
    const int cur = (k0 >> 5) & 1;
    const int nxt = cur ^ 1;
    // ---- issue staging for t+1 into the other buffer (overlaps with compute) ----
    if (k0 < 992) {
      unsigned short* dA = smem + nxt * 4096;
      unsigned short* dB = smem + 8192 + nxt * 4096;
      gload_lds16(A + aoff0 + k0 + 32, dA + stA);
      gload_lds16(A + aoff1 + k0 + 32, dA + stA1i);
      gload_lds16(Bm + boff0 + k0 + 32, dB + stA);
      gload_lds16(Bm + boff1 + k0 + 32, dB + stA1i);
    }
    // ---- compute current buffer ----
    const unsigned short* sA = smem + cur * 4096;
    const unsigned short* sB = smem + 8192 + cur * 4096;
    bfrag af[4], bf[4];
#pragma unroll
    for (int i = 0; i < 4; ++i) af[i] = *(const bfrag*)(sA + (wm * 64 + i * 16 + l16) * 32 + quad * 8);
#pragma unroll
    for (int j = 0; j < 4; ++j) bf[j] = *(const bfrag*)(sB + (wn * 64 + j * 16 + l16) * 32 + quad * 8);
#pragma unroll
    for (int i = 0; i < 4; ++i)
#pragma unroll
      for (int j = 0; j < 4; ++j)
        acc[i][j] = __builtin_amdgcn_mfma_f32_16x16x32_bf16(af[i], bf[j], acc[i][j], 0, 0, 0);
    // ---- one barrier: drains DMA (vmcnt0) + all waves done reading cur ----
    __syncthreads();
  }

  if (z < 2) {
#pragma unroll
    for (int i = 0; i < 4; ++i)
#pragma unroll
      for (int j = 0; j < 4; ++j) {
        const int col = n0 + wn * 64 + j * 16 + l16;
        const float bv = bias[col];
        const int h = col >> 6, d = col & 63;
#pragma unroll
        for (int r = 0; r < 4; ++r) {
          const int m = m0 + wm * 64 + i * 16 + quad * 4 + r;
          const int b = m >> 10, s = m & 1023;
          out[(((size_t)(b * NHd + h) * Sd) + s) * DKd + d] = f2bf(acc[i][j][r] + bv);
        }
      }
  } else {
    unsigned short* sT = smem;  // 128 x 136 (padded), reuses dbuf area (post-barrier)
#pragma unroll
    for (int i = 0; i < 4; ++i)
#pragma unroll
      for (int j = 0; j < 4; ++j) {
        const int col = n0 + wn * 64 + j * 16 + l16;
        const float bv = bias[col];
        const int nrow = wn * 64 + j * 16 + l16;
        const int mbase = wm * 64 + i * 16 + quad * 4;
        ushort4 pk;
        pk.x = f2bf(acc[i][j][0] + bv);
        pk.y = f2bf(acc[i][j][1] + bv);
        pk.z = f2bf(acc[i][j][2] + bv);
        pk.w = f2bf(acc[i][j][3] + bv);
        *(ushort4*)(sT + nrow * 136 + mbase) = pk;
      }
    __syncthreads();
    const int bI = m0 >> 10, s0i = m0 & 1023;
#pragma unroll
    for (int it = 0; it < 8; ++it) {
      const int c = tid + it * 256;
      const int row = c >> 4, mc = (c & 15) * 8;
      bfrag vv = *(const bfrag*)(sT + row * 136 + mc);
      const int col = n0 + row, hh = col >> 6, dd = col & 63;
      *(bfrag*)(out + (((size_t)(bI * NHd + hh) * DKd) + dd) * Sd + s0i + mc) = vv;
    }
  }
}

// ---------------- output projection GEMM: 64x128 tile, BK=64, swizzled LDS, 2-phase ----------------
__global__ __launch_bounds__(256, 3)
void gemm_out(const unsigned short* __restrict__ A, const unsigned short* __restrict__ Bm,
              const float* __restrict__ bias, float* __restrict__ out) {
  // layout: [A0 | A1 | B0 | B1] : A buf 64x64 (4096 us), B buf 128x64 (8192 us) = 48 KB
  __shared__ __align__(16) unsigned short smem[24576];
  const int m0 = blockIdx.x * 64, n0 = blockIdx.y * 128;
  const int tid = threadIdx.x;
  const int wave = tid >> 6, lane = tid & 63;
  const int quad = lane >> 4, l16 = lane & 15;

  facc acc[8] = {};

  // staging: chunk c holds row=c>>3, logical k-chunk (c&7), stored XOR-swizzled
  const int cA0 = (wave * 2 + 0) * 64 + lane;
  const int cA1 = (wave * 2 + 1) * 64 + lane;
  const int rA0 = cA0 >> 3, kA0 = ((cA0 & 7) ^ (rA0 & 7)) * 8;
  const int rA1 = cA1 >> 3, kA1 = ((cA1 & 7) ^ (rA1 & 7)) * 8;
  const size_t aoff0 = (size_t)(m0 + rA0) * 1024 + kA0;
  const size_t aoff1 = (size_t)(m0 + rA1) * 1024 + kA1;
  size_t boff[4];
#pragma unroll
  for (int i = 0; i < 4; ++i) {
    const int c = (wave * 4 + i) * 64 + lane;
    const int r = c >> 3, kk = ((c & 7) ^ (r & 7)) * 8;
    boff[i] = (size_t)(n0 + r) * 1024 + kk;
  }

  const int stA0 = (wave * 2 + 0) * 512;
  const int stA1i = (wave * 2 + 1) * 512;

  // prologue: stage K-step 0 into buffer 0
  gload_lds16(A + aoff0, smem + stA0);
  gload_lds16(A + aoff1, smem + stA1i);
#pragma unroll
  for (int i = 0; i < 4; ++i)
    gload_lds16(Bm + boff[i], smem + 8192 + (wave * 4 + i) * 512);
  __syncthreads();

  for (int k0 = 0; k0 < 1024; k0 += 64) {
    const int cur = (k0 >> 6) & 1;
    const int nxt = cur ^ 1;
    // ---- issue staging for t+1 (overlaps compute) ----
    if (k0 < 960) {
      unsigned short* dA = smem + nxt * 4096;
      unsigned short* dB = smem + 8192 + nxt * 8192;
      gload_lds16(A + aoff0 + k0 + 64, dA + stA0);
      gload_lds16(A + aoff1 + k0 + 64, dA + stA1i);
#pragma unroll
      for (int i = 0; i < 4; ++i)
        gload_lds16(Bm + boff[i] + k0 + 64, dB + (wave * 4 + i) * 512);
    }
    // ---- compute current buffer ----
    const unsigned short* sA = smem + cur * 4096;
    const unsigned short* sB = smem + 8192 + cur * 8192;
#pragma unroll
    for (int c2 = 0; c2 < 2; ++c2) {
      const int ko = ((c2 * 4 + quad) ^ (l16 & 7)) * 8;   // unswizzle
      bfrag af = *(const bfrag*)(sA + (wave * 16 + l16) * 64 + ko);
#pragma unroll
      for (int j = 0; j < 8; ++j) {
        bfrag bf = *(const bfrag*)(sB + (j * 16 + l16) * 64 + ko);
        acc[j] = __builtin_amdgcn_mfma_f32_16x16x32_bf16(af, bf, acc[j], 0, 0, 0);
      }
    }
    __syncthreads();
  }

#pragma unroll
  for (int j = 0; j < 8; ++j) {
    const int col = n0 + j * 16 + l16;
    const float bv = bias[col];
#pragma unroll
    for (int r = 0; r < 4; ++r) {
      const int m = m0 + wave * 16 + quad * 4 + r;
      out[(size_t)m * 1024 + col] = acc[j][r] + bv;
    }
  }
}

// ---------------- fused flash attention: LDS-staged K/V shared by 8 waves ----------------
// (unchanged from r7 — ~91us inferred; serves as the control this round)
__global__ __attribute__((amdgpu_flat_work_group_size(512, 512), amdgpu_waves_per_eu(4, 4)))
void attn_kernel(const unsigned short* __restrict__ q,   // [B,NH,S,DK]
                 const unsigned short* __restrict__ k,   // [B,NH,S,DK]
                 const unsigned short* __restrict__ vt,  // [B,NH,DK,S]
                 const float* __restrict__ bias,         // [B,NH,S,S]
                 unsigned short* __restrict__ o)         // [B,S,HID] bf16
{
  __shared__ __align__(16) unsigned short sK[2][64 * 64];  // 2 x 8 KB, swizzled
  __shared__ __align__(16) unsigned short sV[2][64 * 64];  // 2 x 8 KB, swizzled
  __shared__ __align__(16) unsigned int sP[8][16][36];     // 18 KB packed-P (per wave)

  const int p = blockIdx.x;
  const int xcd = p & 7;
  const int g = p >> 3;                   // 0..63
  const int bh = ((g >> 3) << 3) | xcd;   // 8 bh per XCD (bijective)
  const int qblk = g & 7;
  const int tid = threadIdx.x;
  const int wave = tid >> 6, lane = tid & 63;
  const int quad = lane >> 4, l16 = lane & 15;
  const int b = bh >> 4, h = bh & 15;

  const unsigned short* qh = q + (size_t)bh * Sd * DKd;
  const unsigned short* kh = k + (size_t)bh * Sd * DKd;
  const unsigned short* vh = vt + (size_t)bh * DKd * Sd;
  const float* bias_h = bias + (size_t)bh * Sd * Sd;
  const int rq = qblk * 128 + wave * 16;
  unsigned int (*sPw)[36] = sP[wave];

  const int srow = wave * 8 + (lane >> 3);
  const int sslot = (lane & 7) ^ (srow & 7);
  const unsigned short* srcK = kh + (size_t)srow * DKd + sslot * 8;
  const unsigned short* srcV = vh + (size_t)srow * Sd + sslot * 8;
  unsigned short* dK0 = sK[0] + wave * 512;
  unsigned short* dK1 = sK[1] + wave * 512;
  unsigned short* dV0 = sV[0] + wave * 512;
  unsigned short* dV1 = sV[1] + wave * 512;

  const int xs0 = ((0 + quad) ^ (l16 & 7)) * 8;
  const int xs1 = ((4 + quad) ^ (l16 & 7)) * 8;

  bfrag qf[2];
#pragma unroll
  for (int c = 0; c < 2; ++c)
    qf[c] = *(const bfrag*)(qh + (size_t)(rq + l16) * DKd + c * 32 + quad * 8);

  facc oacc[4] = {};
  float lsum = 0.f;
  const float SL2 = SCALEF * L2E;

  const float* bpS = bias_h + (size_t)(rq + l16) * Sd + quad * 4;
  f32x4 br0 = __builtin_nontemporal_load((const f32x4*)(bpS + 0));
  f32x4 br1 = __builtin_nontemporal_load((const f32x4*)(bpS + 16));
  f32x4 br2 = __builtin_nontemporal_load((const f32x4*)(bpS + 32));
  f32x4 br3 = __builtin_nontemporal_load((const f32x4*)(bpS + 48));

  gload_lds16(srcK, dK0);
  gload_lds16(srcV, dV0);
  __syncthreads();

  for (int t = 0; t < 16; ++t) {
    const int bb = t & 1;
    if (t < 15) {
      const int kn = (t + 1) * 64;
      gload_lds16(srcK + (size_t)kn * DKd, bb ? dK0 : dK1);
      gload_lds16(srcV + kn, bb ? dV0 : dV1);
    }
    const unsigned short* sKb = sK[bb];
    const unsigned short* sVb = sV[bb];
    facc sacc[4] = {};
#pragma unroll
    for (int j = 0; j < 4; ++j) {
      bfrag kf = *(const bfrag*)(sKb + (j * 16 + l16) * 64 + xs0);
      sacc[j] = __builtin_amdgcn_mfma_f32_16x16x32_bf16(kf, qf[0], sacc[j], 0, 0, 0);
    }
#pragma unroll
    for (int j = 0; j < 4; ++j) {
      bfrag kf = *(const bfrag*)(sKb + (j * 16 + l16) * 64 + xs1);
      sacc[j] = __builtin_amdgcn_mfma_f32_16x16x32_bf16(kf, qf[1], sacc[j], 0, 0, 0);
    }
    asm volatile("" : "+v"(br0), "+v"(br1), "+v"(br2), "+v"(br3));
    unsigned int pk[4][2];
#pragma unroll
    for (int j = 0; j < 4; ++j) {
      const f32x4 bv = (j == 0) ? br0 : (j == 1) ? br1 : (j == 2) ? br2 : br3;
      float e0 = __builtin_amdgcn_exp2f(fmaf(sacc[j][0], SL2, bv.x * L2E));
      float e1 = __builtin_amdgcn_exp2f(fmaf(sacc[j][1], SL2, bv.y * L2E));
      float e2 = __builtin_amdgcn_exp2f(fmaf(sacc[j][2], SL2, bv.z * L2E));
      float e3 = __builtin_amdgcn_exp2f(fmaf(sacc[j][3], SL2, bv.w * L2E));
      e0 = (sacc[j][0] == 0.f) ? 0.f : e0;
      e1 = (sacc[j][1] == 0.f) ? 0.f : e1;
      e2 = (sacc[j][2] == 0.f) ? 0.f : e2;
      e3 = (sacc[j][3] == 0.f) ? 0.f : e3;
      lsum += (e0 + e1) + (e2 + e3);
      pk[j][0] = (unsigned int)f2bf(e0) | ((unsigned int)f2bf(e1) << 16);
      pk[j][1] = (unsigned int)f2bf(e2) | ((unsigned int)f2bf(e3) << 16);
    }
    if (t < 15) {
      const float* bpn = bpS + (t + 1) * 64;
      br0 = __builtin_nontemporal_load((const f32x4*)(bpn + 0));
      br1 = __builtin_nontemporal_load((const f32x4*)(bpn + 16));
      br2 = __builtin_nontemporal_load((const f32x4*)(bpn + 32));
      br3 = __builtin_nontemporal_load((const f32x4*)(bpn + 48));
    }
#pragma unroll
    for (int j = 0; j < 4; ++j) {
      uint2 w; w.x = pk[j][0]; w.y = pk[j][1];
      *(uint2*)&sPw[l16][j * 8 + quad * 2] = w;
    }
#pragma unroll
    for (int c = 0; c < 2; ++c) {
      bfrag pf = *(const bfrag*)&sPw[l16][c * 16 + quad * 4];
      const int xsc = c ? xs1 : xs0;
#pragma unroll
      for (int n = 0; n < 4; ++n) {
        bfrag vf = *(const bfrag*)(sVb + (n * 16 + l16) * 64 + xsc);
        oacc[n] = __builtin_amdgcn_mfma_f32_16x16x32_bf16(vf, pf, oacc[n], 0, 0, 0);
      }
    }
    __syncthreads();
  }

  lsum += __shfl_xor(lsum, 16, 64);
  lsum += __shfl_xor(lsum, 32, 64);
  const float rinv = 1.0f / lsum;

  const size_t rowo = (size_t)(b * Sd + rq + l16) * Hd + h * 64 + quad * 4;
#pragma unroll
  for (int n = 0; n < 4; ++n) {
    ushort4 st;
    st.x = f2bf(oacc[n][0] * rinv);
    st.y = f2bf(oacc[n][1] * rinv);
    st.z = f2bf(oacc[n][2] * rinv);
    st.w = f2bf(oacc[n][3] * rinv);
    *(ushort4*)(o + rowo + n * 16) = st;
  }
}

extern "C" void kernel_launch(void* const* d_in, const int* in_sizes, int n_in,
                              void* d_out, int out_size, void* d_ws, size_t ws_size,
                              hipStream_t stream) {
  const float* batch = (const float*)d_in[0];
  const float* attn_bias = (const float*)d_in[1];
  const float* Wq = (const float*)d_in[2];
  const float* bq = (const float*)d_in[3];
  const float* Wk = (const float*)d_in[4];
  const float* bk = (const float*)d_in[5];
  const float* Wv = (const float*)d_in[6];
  const float* bv = (const float*)d_in[7];
  const float* Wo = (const float*)d_in[8];
  const float* bo = (const float*)d_in[9];
  float* out = (float*)d_out;

  unsigned short* ws = (unsigned short*)d_ws;
  unsigned short* Ab  = ws;                 // 4096x1024
  unsigned short* Wqb = Ab  + 4194304;      // 1024x1024 each
  unsigned short* Wkb = Wqb + 1048576;
  unsigned short* Wvb = Wkb + 1048576;
  unsigned short* Wob = Wvb + 1048576;
  unsigned short* qb  = Wob + 1048576;      // [B,NH,S,DK]
  unsigned short* kb  = qb  + 4194304;
  unsigned short* vtb = kb  + 4194304;      // [B,NH,DK,S]
  unsigned short* ob  = vtb + 4194304;      // [B,S,HID]

  castk_all<<<8192, 256, 0, stream>>>(batch, Wq, Wk, Wv, Wo, Ab, Wqb, Wkb, Wvb, Wob);
  gemm_qkv<<<dim3(32, 8, 3), 256, 0, stream>>>(Ab, Wqb, Wkb, Wvb, bq, bk, bv, qb, kb, vtb);
  attn_kernel<<<dim3(512), 512, 0, stream>>>(qb, kb, vtb, attn_bias, ob);
  gemm_out<<<dim3(64, 8), 256, 0, stream>>>(ob, Wob, bo, out);
}